// Round 4
// baseline (749.691 us; speedup 1.0000x reference)
//
#include <hip/hip_runtime.h>

#define N_NODES 50000
#define N_EDGES 800000
#define N_GRAPHS 512
#define IN_C 128
#define HID 256
#define OUT_C 16

typedef __attribute__((ext_vector_type(8))) short short8;
typedef __attribute__((ext_vector_type(4))) float f32x4;

__device__ __forceinline__ float bf2f(unsigned short u) {
    return __uint_as_float(((unsigned int)u) << 16);
}
__device__ __forceinline__ unsigned short f2bf(float f) {
    unsigned int u = __float_as_uint(f);
    u += 0x7fff + ((u >> 16) & 1);   // RNE
    return (unsigned short)(u >> 16);
}

// ===========================================================================
// Prep: fp32 -> bf16 casts.
// ===========================================================================
__global__ void cast_x_kernel(const float* __restrict__ in, ushort* __restrict__ out, int n4) {
    int i = blockIdx.x * blockDim.x + threadIdx.x;
    if (i >= n4) return;
    float4 v = *(const float4*)(in + (long)i * 4);
    ushort4 o;
    o.x = f2bf(v.x); o.y = f2bf(v.y); o.z = f2bf(v.z); o.w = f2bf(v.w);
    *(ushort4*)(out + (long)i * 4) = o;
}

// w: K x N fp32 (row-major) -> wt: N x K bf16 (transposed)
__global__ void transpose_cast_kernel(const float* __restrict__ w, ushort* __restrict__ wt,
                                      int K, int N) {
    int i = blockIdx.x * blockDim.x + threadIdx.x;
    if (i >= N * K) return;
    int n = i / K;
    int k = i - n * K;
    wt[i] = f2bf(w[(long)k * N + n]);
}

// ===========================================================================
// CSR build: deg histogram -> 2-level exclusive scan -> bucket edges by dst.
// ===========================================================================
__global__ void deg_kernel(const int* __restrict__ dst, int* __restrict__ deg) {
    int e = blockIdx.x * blockDim.x + threadIdx.x;
    if (e < N_EDGES) atomicAdd(&deg[dst[e]], 1);
}

__global__ __launch_bounds__(256) void scan_block(const int* __restrict__ deg,
                                                  int* __restrict__ partial,
                                                  int* __restrict__ blockSums) {
    __shared__ int s[256];
    int t = threadIdx.x;
    int i = blockIdx.x * 256 + t;
    int v = (i < N_NODES) ? deg[i] : 0;
    s[t] = v;
    __syncthreads();
    #pragma unroll
    for (int off = 1; off < 256; off <<= 1) {
        int add = (t >= off) ? s[t - off] : 0;
        __syncthreads();
        s[t] += add;
        __syncthreads();
    }
    if (i < N_NODES) partial[i] = s[t] - v;
    if (t == 255) blockSums[blockIdx.x] = s[255];
}

__global__ __launch_bounds__(256) void scan_sums(int* __restrict__ blockSums, int nb) {
    __shared__ int s[256];
    int t = threadIdx.x;
    int v = (t < nb) ? blockSums[t] : 0;
    s[t] = v;
    __syncthreads();
    #pragma unroll
    for (int off = 1; off < 256; off <<= 1) {
        int add = (t >= off) ? s[t - off] : 0;
        __syncthreads();
        s[t] += add;
        __syncthreads();
    }
    if (t < nb) blockSums[t] = s[t] - v;
}

__global__ void add_offsets(const int* __restrict__ partial,
                            const int* __restrict__ blockSums,
                            int* __restrict__ rowptr) {
    int i = blockIdx.x * 256 + threadIdx.x;
    if (i < N_NODES) rowptr[i] = partial[i] + blockSums[blockIdx.x];
    if (i == 0) rowptr[N_NODES] = N_EDGES;
}

__global__ void bucket_edges(const int* __restrict__ src, const int* __restrict__ dst,
                             int* __restrict__ cursor, int* __restrict__ srcSorted) {
    int e = blockIdx.x * blockDim.x + threadIdx.x;
    if (e >= N_EDGES) return;
    int p = atomicAdd(&cursor[dst[e]], 1);
    srcSorted[p] = src[e];
}

// ===========================================================================
// Fused GIN layer: per 64-node block:
//   Phase A: agg = h[n] + sum h[src]  -> LDS As (bf16, chunked+padded)
//   Phase B: h1 = relu(agg @ W1 + b1) -> LDS Hs
//   Phase C: out = relu(h1 @ W2 + b2) -> global
// LDS layout: element (m,k) at slot(q=k>>3, m), short-offset (q*65+m)*8 + (k&7).
// Pitch 65 (16B slots) breaks the gather-store transpose conflict to ~4-way.
// B-fragments are read directly from L2-resident transposed weights.
// ===========================================================================
template <int CIN>
__global__ __launch_bounds__(256) void gin_layer(
    const ushort* __restrict__ hin,   // N_NODES x CIN bf16
    const int* __restrict__ rowptr,
    const int* __restrict__ srcIdx,
    const ushort* __restrict__ w1t,   // 256 x CIN bf16 (N x K)
    const float* __restrict__ b1,
    const ushort* __restrict__ w2t,   // 256 x 256 bf16 (N x K)
    const float* __restrict__ b2,
    ushort* __restrict__ hout)        // N_NODES x 256 bf16
{
    constexpr int VEC = CIN / 64;     // 4 (CIN=256) or 2 (CIN=128)
    constexpr int NQ = CIN / 8;       // chunks per row
    __shared__ short As[NQ * 65 * 8];
    __shared__ short Hs[32 * 65 * 8];

    int t = threadIdx.x;
    int lane = t & 63;
    int wv = t >> 6;
    int quad = lane >> 4;
    int l15 = lane & 15;
    int base = blockIdx.x * 64;

    // ---------------- Phase A: gather into As ----------------
    {
        int coff = lane * VEC;
        for (int i = 0; i < 16; ++i) {
            int node = base + wv * 16 + i;
            int m = wv * 16 + i;
            float acc[VEC];
            #pragma unroll
            for (int v = 0; v < VEC; ++v) acc[v] = 0.f;
            if (node < N_NODES) {
                const ushort* hp = hin + (long)node * CIN + coff;
                if constexpr (VEC == 4) {
                    ushort4 s = *(const ushort4*)hp;
                    acc[0] = bf2f(s.x); acc[1] = bf2f(s.y); acc[2] = bf2f(s.z); acc[3] = bf2f(s.w);
                } else {
                    ushort2 s = *(const ushort2*)hp;
                    acc[0] = bf2f(s.x); acc[1] = bf2f(s.y);
                }
                int beg = rowptr[node], end = rowptr[node + 1];
                int k = beg;
                for (; k + 4 <= end; k += 4) {
                    int s0 = srcIdx[k + 0], s1 = srcIdx[k + 1];
                    int s2 = srcIdx[k + 2], s3 = srcIdx[k + 3];
                    if constexpr (VEC == 4) {
                        ushort4 r0 = *(const ushort4*)(hin + (long)s0 * CIN + coff);
                        ushort4 r1 = *(const ushort4*)(hin + (long)s1 * CIN + coff);
                        ushort4 r2 = *(const ushort4*)(hin + (long)s2 * CIN + coff);
                        ushort4 r3 = *(const ushort4*)(hin + (long)s3 * CIN + coff);
                        acc[0] += bf2f(r0.x) + bf2f(r1.x) + bf2f(r2.x) + bf2f(r3.x);
                        acc[1] += bf2f(r0.y) + bf2f(r1.y) + bf2f(r2.y) + bf2f(r3.y);
                        acc[2] += bf2f(r0.z) + bf2f(r1.z) + bf2f(r2.z) + bf2f(r3.z);
                        acc[3] += bf2f(r0.w) + bf2f(r1.w) + bf2f(r2.w) + bf2f(r3.w);
                    } else {
                        ushort2 r0 = *(const ushort2*)(hin + (long)s0 * CIN + coff);
                        ushort2 r1 = *(const ushort2*)(hin + (long)s1 * CIN + coff);
                        ushort2 r2 = *(const ushort2*)(hin + (long)s2 * CIN + coff);
                        ushort2 r3 = *(const ushort2*)(hin + (long)s3 * CIN + coff);
                        acc[0] += bf2f(r0.x) + bf2f(r1.x) + bf2f(r2.x) + bf2f(r3.x);
                        acc[1] += bf2f(r0.y) + bf2f(r1.y) + bf2f(r2.y) + bf2f(r3.y);
                    }
                }
                for (; k < end; ++k) {
                    int s = srcIdx[k];
                    if constexpr (VEC == 4) {
                        ushort4 r = *(const ushort4*)(hin + (long)s * CIN + coff);
                        acc[0] += bf2f(r.x); acc[1] += bf2f(r.y);
                        acc[2] += bf2f(r.z); acc[3] += bf2f(r.w);
                    } else {
                        ushort2 r = *(const ushort2*)(hin + (long)s * CIN + coff);
                        acc[0] += bf2f(r.x); acc[1] += bf2f(r.y);
                    }
                }
            }
            // store to As chunk layout
            if constexpr (VEC == 4) {
                int q = lane >> 1;
                ushort4 o;
                o.x = f2bf(acc[0]); o.y = f2bf(acc[1]);
                o.z = f2bf(acc[2]); o.w = f2bf(acc[3]);
                *(ushort4*)&As[(q * 65 + m) * 8 + (lane & 1) * 4] = o;
            } else {
                int q = lane >> 2;
                ushort2 o;
                o.x = f2bf(acc[0]); o.y = f2bf(acc[1]);
                *(ushort2*)&As[(q * 65 + m) * 8 + (lane & 3) * 2] = o;
            }
        }
    }
    __syncthreads();

    const f32x4 zero = {0.f, 0.f, 0.f, 0.f};
    f32x4 acc[4][4];

    // ---------------- Phase B: GEMM1 (K=CIN), h1 -> Hs ----------------
    #pragma unroll
    for (int i = 0; i < 4; ++i)
        #pragma unroll
        for (int j = 0; j < 4; ++j) acc[i][j] = zero;

    #pragma unroll
    for (int s = 0; s < CIN / 32; ++s) {
        short8 a[4], b[4];
        #pragma unroll
        for (int i = 0; i < 4; ++i)
            a[i] = *(const short8*)&As[((s * 4 + quad) * 65 + i * 16 + l15) * 8];
        #pragma unroll
        for (int j = 0; j < 4; ++j) {
            int col = wv * 64 + j * 16 + l15;
            b[j] = *(const short8*)(w1t + (long)col * CIN + s * 32 + quad * 8);
        }
        #pragma unroll
        for (int i = 0; i < 4; ++i)
            #pragma unroll
            for (int j = 0; j < 4; ++j)
                acc[i][j] = __builtin_amdgcn_mfma_f32_16x16x32_bf16(a[i], b[j], acc[i][j], 0, 0, 0);
    }

    {
        float bv[4];
        #pragma unroll
        for (int j = 0; j < 4; ++j) bv[j] = b1[wv * 64 + j * 16 + l15];
        #pragma unroll
        for (int i = 0; i < 4; ++i)
            #pragma unroll
            for (int j = 0; j < 4; ++j) {
                int col = wv * 64 + j * 16 + l15;
                int q2 = col >> 3, sub = col & 7;
                #pragma unroll
                for (int r = 0; r < 4; ++r) {
                    int row = i * 16 + quad * 4 + r;
                    float o = fmaxf(acc[i][j][r] + bv[j], 0.f);
                    Hs[(q2 * 65 + row) * 8 + sub] = (short)f2bf(o);
                }
            }
    }
    __syncthreads();

    // ---------------- Phase C: GEMM2 (K=256) -> global ----------------
    #pragma unroll
    for (int i = 0; i < 4; ++i)
        #pragma unroll
        for (int j = 0; j < 4; ++j) acc[i][j] = zero;

    #pragma unroll
    for (int s = 0; s < 8; ++s) {
        short8 a[4], b[4];
        #pragma unroll
        for (int i = 0; i < 4; ++i)
            a[i] = *(const short8*)&Hs[((s * 4 + quad) * 65 + i * 16 + l15) * 8];
        #pragma unroll
        for (int j = 0; j < 4; ++j) {
            int col = wv * 64 + j * 16 + l15;
            b[j] = *(const short8*)(w2t + (long)col * 256 + s * 32 + quad * 8);
        }
        #pragma unroll
        for (int i = 0; i < 4; ++i)
            #pragma unroll
            for (int j = 0; j < 4; ++j)
                acc[i][j] = __builtin_amdgcn_mfma_f32_16x16x32_bf16(a[i], b[j], acc[i][j], 0, 0, 0);
    }

    {
        float bv[4];
        #pragma unroll
        for (int j = 0; j < 4; ++j) bv[j] = b2[wv * 64 + j * 16 + l15];
        #pragma unroll
        for (int i = 0; i < 4; ++i)
            #pragma unroll
            for (int r = 0; r < 4; ++r) {
                int row = base + i * 16 + quad * 4 + r;
                if (row >= N_NODES) continue;
                #pragma unroll
                for (int j = 0; j < 4; ++j) {
                    int col = wv * 64 + j * 16 + l15;
                    float o = fmaxf(acc[i][j][r] + bv[j], 0.f);
                    hout[(long)row * 256 + col] = f2bf(o);
                }
            }
    }
}

// ===========================================================================
// Mean-pool (bf16 h -> fp32 sums): run-length flush, batch is sorted.
// ===========================================================================
__global__ __launch_bounds__(256) void pool_kernel_bf(const ushort* __restrict__ h,
                                                      const int* __restrict__ batch,
                                                      float* __restrict__ sums) {
    int base = blockIdx.x * 64;
    int t = threadIdx.x;
    int c4 = (t & 63) << 2;
    int r0 = t >> 6;
    float a0 = 0.f, a1 = 0.f, a2 = 0.f, a3 = 0.f;
    int cur = -1;
    for (int i = r0; i < 64; i += 4) {
        int n = base + i;
        if (n >= N_NODES) break;
        int g = batch[n];
        if (g != cur) {
            if (cur >= 0) {
                float* p = sums + (long)cur * HID + c4;
                atomicAdd(p + 0, a0); atomicAdd(p + 1, a1);
                atomicAdd(p + 2, a2); atomicAdd(p + 3, a3);
            }
            cur = g;
            a0 = a1 = a2 = a3 = 0.f;
        }
        ushort4 v = *(const ushort4*)(h + (long)n * HID + c4);
        a0 += bf2f(v.x); a1 += bf2f(v.y); a2 += bf2f(v.z); a3 += bf2f(v.w);
    }
    if (cur >= 0) {
        float* p = sums + (long)cur * HID + c4;
        atomicAdd(p + 0, a0); atomicAdd(p + 1, a1);
        atomicAdd(p + 2, a2); atomicAdd(p + 3, a3);
    }
}

__global__ void count_kernel(const int* __restrict__ batch, float* __restrict__ counts) {
    int n = blockIdx.x * blockDim.x + threadIdx.x;
    if (n < N_NODES) atomicAdd(&counts[batch[n]], 1.0f);
}

// ===========================================================================
// Head MLP (fp32): one block per graph.
// ===========================================================================
__global__ __launch_bounds__(256) void final_mlp_kernel(
    const float* __restrict__ sums, const float* __restrict__ counts,
    const float* __restrict__ w1, const float* __restrict__ b1,
    const float* __restrict__ w2, const float* __restrict__ b2,
    float* __restrict__ out) {
    __shared__ float row[HID];
    __shared__ float hid[HID];
    int g = blockIdx.x;
    int t = threadIdx.x;
    float cnt = fmaxf(counts[g], 1.0f);
    row[t] = sums[(long)g * HID + t] / cnt;
    __syncthreads();
    float acc = b1[t];
    for (int k = 0; k < HID; ++k) acc += row[k] * w1[k * HID + t];
    hid[t] = fmaxf(acc, 0.f);
    __syncthreads();
    if (t < OUT_C) {
        float o = b2[t];
        for (int k = 0; k < HID; ++k) o += hid[k] * w2[k * OUT_C + t];
        out[(long)g * OUT_C + t] = o;
    }
}

// ---------------------------------------------------------------------------
extern "C" void kernel_launch(void* const* d_in, const int* in_sizes, int n_in,
                              void* d_out, int out_size, void* d_ws, size_t ws_size,
                              hipStream_t stream) {
    const float* x     = (const float*)d_in[0];
    const int*   ei    = (const int*)d_in[1];
    const int*   batch = (const int*)d_in[2];
    const int*   src   = ei;
    const int*   dst   = ei + N_EDGES;

    const float* c_w1[3] = { (const float*)d_in[3],  (const float*)d_in[7],  (const float*)d_in[11] };
    const float* c_b1[3] = { (const float*)d_in[4],  (const float*)d_in[8],  (const float*)d_in[12] };
    const float* c_w2[3] = { (const float*)d_in[5],  (const float*)d_in[9],  (const float*)d_in[13] };
    const float* c_b2[3] = { (const float*)d_in[6],  (const float*)d_in[10], (const float*)d_in[14] };
    const float* out_w1 = (const float*)d_in[15];
    const float* out_b1 = (const float*)d_in[16];
    const float* out_w2 = (const float*)d_in[17];
    const float* out_b2 = (const float*)d_in[18];

    // ---- Workspace layout (16B aligned regions) ----
    char* p = (char*)d_ws;
    auto alloc = [&](size_t bytes) {
        char* r = p;
        p += (bytes + 15) & ~(size_t)15;
        return r;
    };
    ushort* xbf  = (ushort*)alloc((size_t)N_NODES * IN_C * 2);
    ushort* bufA = (ushort*)alloc((size_t)N_NODES * HID * 2);
    ushort* bufB = (ushort*)alloc((size_t)N_NODES * HID * 2);
    ushort* wt[6];
    wt[0] = (ushort*)alloc((size_t)IN_C * HID * 2);        // c0_w1^T: 256 x 128
    for (int i = 1; i < 6; ++i) wt[i] = (ushort*)alloc((size_t)HID * HID * 2);
    float* sums   = (float*)alloc((size_t)N_GRAPHS * HID * 4);
    float* counts = (float*)alloc((size_t)N_GRAPHS * 4);
    int* deg       = (int*)alloc((size_t)N_NODES * 4);
    int* rowptr    = (int*)alloc((size_t)(N_NODES + 1) * 4);
    int* blockSums = (int*)alloc(256 * 4);
    int* cursor    = (int*)alloc((size_t)N_NODES * 4);
    int* srcSorted = (int*)alloc((size_t)N_EDGES * 4);

    const int nb = (N_NODES + 255) / 256;

    // ---- Prep: casts ----
    {
        int n4 = N_NODES * IN_C / 4;
        cast_x_kernel<<<(n4 + 255) / 256, 256, 0, stream>>>(x, xbf, n4);
    }
    transpose_cast_kernel<<<(IN_C * HID + 255) / 256, 256, 0, stream>>>(c_w1[0], wt[0], IN_C, HID);
    transpose_cast_kernel<<<(HID * HID + 255) / 256, 256, 0, stream>>>(c_w2[0], wt[1], HID, HID);
    transpose_cast_kernel<<<(HID * HID + 255) / 256, 256, 0, stream>>>(c_w1[1], wt[2], HID, HID);
    transpose_cast_kernel<<<(HID * HID + 255) / 256, 256, 0, stream>>>(c_w2[1], wt[3], HID, HID);
    transpose_cast_kernel<<<(HID * HID + 255) / 256, 256, 0, stream>>>(c_w1[2], wt[4], HID, HID);
    transpose_cast_kernel<<<(HID * HID + 255) / 256, 256, 0, stream>>>(c_w2[2], wt[5], HID, HID);

    // ---- Build CSR by dst ----
    hipMemsetAsync(deg, 0, sizeof(int) * N_NODES, stream);
    deg_kernel<<<(N_EDGES + 255) / 256, 256, 0, stream>>>(dst, deg);
    scan_block<<<nb, 256, 0, stream>>>(deg, rowptr, blockSums);
    scan_sums<<<1, 256, 0, stream>>>(blockSums, nb);
    add_offsets<<<nb, 256, 0, stream>>>(rowptr, blockSums, rowptr);
    hipMemcpyAsync(cursor, rowptr, sizeof(int) * N_NODES, hipMemcpyDeviceToDevice, stream);
    bucket_edges<<<(N_EDGES + 255) / 256, 256, 0, stream>>>(src, dst, cursor, srcSorted);

    const int layerGrid = (N_NODES + 63) / 64;   // 782

    // ---- Fused GIN layers ----
    gin_layer<IN_C><<<layerGrid, 256, 0, stream>>>(xbf, rowptr, srcSorted,
                                                   wt[0], c_b1[0], wt[1], c_b2[0], bufA);
    gin_layer<HID><<<layerGrid, 256, 0, stream>>>(bufA, rowptr, srcSorted,
                                                  wt[2], c_b1[1], wt[3], c_b2[1], bufB);
    gin_layer<HID><<<layerGrid, 256, 0, stream>>>(bufB, rowptr, srcSorted,
                                                  wt[4], c_b1[2], wt[5], c_b2[2], bufA);

    // ---- Global mean pool ----
    hipMemsetAsync(sums, 0, sizeof(float) * (size_t)N_GRAPHS * HID, stream);
    hipMemsetAsync(counts, 0, sizeof(float) * N_GRAPHS, stream);
    pool_kernel_bf<<<(N_NODES + 63) / 64, 256, 0, stream>>>(bufA, batch, sums);
    count_kernel<<<(N_NODES + 255) / 256, 256, 0, stream>>>(batch, counts);

    // ---- Head MLP (fp32) ----
    final_mlp_kernel<<<N_GRAPHS, 256, 0, stream>>>(sums, counts, out_w1, out_b1,
                                                   out_w2, out_b2, (float*)d_out);
}

// Round 5
// 643.057 us; speedup vs baseline: 1.1658x; 1.1658x over previous
//
#include <hip/hip_runtime.h>

#define N_NODES 50000
#define N_EDGES 800000
#define N_GRAPHS 512
#define IN_C 128
#define HID 256
#define OUT_C 16

typedef __attribute__((ext_vector_type(8))) short short8;
typedef __attribute__((ext_vector_type(4))) float f32x4;

__device__ __forceinline__ float bf2f(unsigned short u) {
    return __uint_as_float(((unsigned int)u) << 16);
}
__device__ __forceinline__ unsigned short f2bf(float f) {
    unsigned int u = __float_as_uint(f);
    u += 0x7fff + ((u >> 16) & 1);   // RNE
    return (unsigned short)(u >> 16);
}

// ===========================================================================
// Prep: fp32 -> bf16 casts.
// ===========================================================================
__global__ void cast_x_kernel(const float* __restrict__ in, ushort* __restrict__ out, int n4) {
    int i = blockIdx.x * blockDim.x + threadIdx.x;
    if (i >= n4) return;
    float4 v = *(const float4*)(in + (long)i * 4);
    ushort4 o;
    o.x = f2bf(v.x); o.y = f2bf(v.y); o.z = f2bf(v.z); o.w = f2bf(v.w);
    *(ushort4*)(out + (long)i * 4) = o;
}

// w: K x N fp32 (row-major) -> wt: N x K bf16 (transposed)
__global__ void transpose_cast_kernel(const float* __restrict__ w, ushort* __restrict__ wt,
                                      int K, int N) {
    int i = blockIdx.x * blockDim.x + threadIdx.x;
    if (i >= N * K) return;
    int n = i / K;
    int k = i - n * K;
    wt[i] = f2bf(w[(long)k * N + n]);
}

// ===========================================================================
// CSR build: deg histogram -> 2-level exclusive scan -> bucket edges by dst.
// ===========================================================================
__global__ void deg_kernel(const int* __restrict__ dst, int* __restrict__ deg) {
    int e = blockIdx.x * blockDim.x + threadIdx.x;
    if (e < N_EDGES) atomicAdd(&deg[dst[e]], 1);
}

__global__ __launch_bounds__(256) void scan_block(const int* __restrict__ deg,
                                                  int* __restrict__ partial,
                                                  int* __restrict__ blockSums) {
    __shared__ int s[256];
    int t = threadIdx.x;
    int i = blockIdx.x * 256 + t;
    int v = (i < N_NODES) ? deg[i] : 0;
    s[t] = v;
    __syncthreads();
    #pragma unroll
    for (int off = 1; off < 256; off <<= 1) {
        int add = (t >= off) ? s[t - off] : 0;
        __syncthreads();
        s[t] += add;
        __syncthreads();
    }
    if (i < N_NODES) partial[i] = s[t] - v;
    if (t == 255) blockSums[blockIdx.x] = s[255];
}

__global__ __launch_bounds__(256) void scan_sums(int* __restrict__ blockSums, int nb) {
    __shared__ int s[256];
    int t = threadIdx.x;
    int v = (t < nb) ? blockSums[t] : 0;
    s[t] = v;
    __syncthreads();
    #pragma unroll
    for (int off = 1; off < 256; off <<= 1) {
        int add = (t >= off) ? s[t - off] : 0;
        __syncthreads();
        s[t] += add;
        __syncthreads();
    }
    if (t < nb) blockSums[t] = s[t] - v;
}

__global__ void add_offsets(const int* __restrict__ partial,
                            const int* __restrict__ blockSums,
                            int* __restrict__ rowptr) {
    int i = blockIdx.x * 256 + threadIdx.x;
    if (i < N_NODES) rowptr[i] = partial[i] + blockSums[blockIdx.x];
    if (i == 0) rowptr[N_NODES] = N_EDGES;
}

__global__ void bucket_edges(const int* __restrict__ src, const int* __restrict__ dst,
                             int* __restrict__ cursor, int* __restrict__ srcSorted) {
    int e = blockIdx.x * blockDim.x + threadIdx.x;
    if (e >= N_EDGES) return;
    int p = atomicAdd(&cursor[dst[e]], 1);
    srcSorted[p] = src[e];
}

// ===========================================================================
// Aggregation (bf16, fp32 accumulate): out[n] = h[n] + sum h[src].
// One wave per node; lane owns C/64 channels; neighbor loop unrolled x4 so
// 4 independent gathers are in flight per issue slot.
// ===========================================================================
template <int C>
__global__ __launch_bounds__(256) void gin_aggregate_bf(const ushort* __restrict__ h,
                                                        const int* __restrict__ rowptr,
                                                        const int* __restrict__ srcIdx,
                                                        ushort* __restrict__ out) {
    constexpr int VEC = C / 64;   // 4 (C=256) or 2 (C=128)
    int wave = threadIdx.x >> 6;
    int lane = threadIdx.x & 63;
    int node = blockIdx.x * 4 + wave;
    if (node >= N_NODES) return;
    int coff = lane * VEC;

    float acc[VEC];
    {
        const ushort* hp = h + (long)node * C + coff;
        if constexpr (VEC == 4) {
            ushort4 s = *(const ushort4*)hp;
            acc[0] = bf2f(s.x); acc[1] = bf2f(s.y); acc[2] = bf2f(s.z); acc[3] = bf2f(s.w);
        } else {
            ushort2 s = *(const ushort2*)hp;
            acc[0] = bf2f(s.x); acc[1] = bf2f(s.y);
        }
    }

    int beg = rowptr[node], end = rowptr[node + 1];
    int k = beg;
    for (; k + 4 <= end; k += 4) {
        int s0 = srcIdx[k + 0], s1 = srcIdx[k + 1];
        int s2 = srcIdx[k + 2], s3 = srcIdx[k + 3];
        if constexpr (VEC == 4) {
            ushort4 r0 = *(const ushort4*)(h + (long)s0 * C + coff);
            ushort4 r1 = *(const ushort4*)(h + (long)s1 * C + coff);
            ushort4 r2 = *(const ushort4*)(h + (long)s2 * C + coff);
            ushort4 r3 = *(const ushort4*)(h + (long)s3 * C + coff);
            acc[0] += bf2f(r0.x) + bf2f(r1.x) + bf2f(r2.x) + bf2f(r3.x);
            acc[1] += bf2f(r0.y) + bf2f(r1.y) + bf2f(r2.y) + bf2f(r3.y);
            acc[2] += bf2f(r0.z) + bf2f(r1.z) + bf2f(r2.z) + bf2f(r3.z);
            acc[3] += bf2f(r0.w) + bf2f(r1.w) + bf2f(r2.w) + bf2f(r3.w);
        } else {
            ushort2 r0 = *(const ushort2*)(h + (long)s0 * C + coff);
            ushort2 r1 = *(const ushort2*)(h + (long)s1 * C + coff);
            ushort2 r2 = *(const ushort2*)(h + (long)s2 * C + coff);
            ushort2 r3 = *(const ushort2*)(h + (long)s3 * C + coff);
            acc[0] += bf2f(r0.x) + bf2f(r1.x) + bf2f(r2.x) + bf2f(r3.x);
            acc[1] += bf2f(r0.y) + bf2f(r1.y) + bf2f(r2.y) + bf2f(r3.y);
        }
    }
    for (; k < end; ++k) {
        int s = srcIdx[k];
        if constexpr (VEC == 4) {
            ushort4 r = *(const ushort4*)(h + (long)s * C + coff);
            acc[0] += bf2f(r.x); acc[1] += bf2f(r.y); acc[2] += bf2f(r.z); acc[3] += bf2f(r.w);
        } else {
            ushort2 r = *(const ushort2*)(h + (long)s * C + coff);
            acc[0] += bf2f(r.x); acc[1] += bf2f(r.y);
        }
    }

    ushort* op = out + (long)node * C + coff;
    if constexpr (VEC == 4) {
        ushort4 o;
        o.x = f2bf(acc[0]); o.y = f2bf(acc[1]); o.z = f2bf(acc[2]); o.w = f2bf(acc[3]);
        *(ushort4*)op = o;
    } else {
        ushort2 o;
        o.x = f2bf(acc[0]); o.y = f2bf(acc[1]);
        *(ushort2*)op = o;
    }
}

// ===========================================================================
// Direct MFMA GEMM, no LDS, no barriers: C[M,256] = A[M,K] @ W[K,256] (+bias,
// +ReLU), bf16 in/out. Wt is N x K (transposed). Block = 4 waves; wave wv
// owns a 64x64 tile at cols wv*64, rows blockIdx.x*64. A-frags and B-frags
// are loaded straight from global (16-row x 64B runs; W is 128KB, L2-hot;
// A streams once). Fully unrolled K-loop: 64 loads + 128 MFMAs, 0 syncs.
// ===========================================================================
template <int K>
__global__ __launch_bounds__(256) void gemm_direct(
    const ushort* __restrict__ A,   // M x K bf16
    const ushort* __restrict__ Wt,  // 256 x K bf16
    const float* __restrict__ bias, // 256 fp32
    ushort* __restrict__ C,         // M x 256 bf16
    int M, int doRelu)
{
    int t = threadIdx.x;
    int lane = t & 63;
    int wv = t >> 6;
    int quad = lane >> 4;
    int l15 = lane & 15;
    int row0 = blockIdx.x * 64;
    int col0 = wv * 64;

    const f32x4 zero = {0.f, 0.f, 0.f, 0.f};
    f32x4 acc[4][4];
    #pragma unroll
    for (int i = 0; i < 4; ++i)
        #pragma unroll
        for (int j = 0; j < 4; ++j) acc[i][j] = zero;

    // a-frag for frag-row i: lane reads A[row0 + i*16 + l15][s*32 + quad*8 ..+8]
    // clamp row for the (only) partial last block; stores are guarded.
    long arow[4];
    #pragma unroll
    for (int i = 0; i < 4; ++i) {
        int r = row0 + i * 16 + l15;
        if (r >= M) r = M - 1;
        arow[i] = (long)r * K;
    }
    long brow[4];
    #pragma unroll
    for (int j = 0; j < 4; ++j)
        brow[j] = (long)(col0 + j * 16 + l15) * K;

    #pragma unroll
    for (int s = 0; s < K / 32; ++s) {
        int ko = s * 32 + quad * 8;
        short8 a[4], b[4];
        #pragma unroll
        for (int i = 0; i < 4; ++i) a[i] = *(const short8*)(A + arow[i] + ko);
        #pragma unroll
        for (int j = 0; j < 4; ++j) b[j] = *(const short8*)(Wt + brow[j] + ko);
        #pragma unroll
        for (int i = 0; i < 4; ++i)
            #pragma unroll
            for (int j = 0; j < 4; ++j)
                acc[i][j] = __builtin_amdgcn_mfma_f32_16x16x32_bf16(a[i], b[j], acc[i][j], 0, 0, 0);
    }

    // Epilogue: C/D layout col = l15, row = quad*4 + r.
    float bv[4];
    #pragma unroll
    for (int j = 0; j < 4; ++j) bv[j] = bias[col0 + j * 16 + l15];

    #pragma unroll
    for (int i = 0; i < 4; ++i)
        #pragma unroll
        for (int r = 0; r < 4; ++r) {
            int row = row0 + i * 16 + quad * 4 + r;
            if (row >= M) continue;
            #pragma unroll
            for (int j = 0; j < 4; ++j) {
                float o = acc[i][j][r] + bv[j];
                if (doRelu) o = fmaxf(o, 0.f);
                C[(long)row * 256 + col0 + j * 16 + l15] = f2bf(o);
            }
        }
}

// ===========================================================================
// Mean-pool (bf16 h -> fp32 sums): run-length flush, batch is sorted.
// ===========================================================================
__global__ __launch_bounds__(256) void pool_kernel_bf(const ushort* __restrict__ h,
                                                      const int* __restrict__ batch,
                                                      float* __restrict__ sums) {
    int base = blockIdx.x * 64;
    int t = threadIdx.x;
    int c4 = (t & 63) << 2;
    int r0 = t >> 6;
    float a0 = 0.f, a1 = 0.f, a2 = 0.f, a3 = 0.f;
    int cur = -1;
    for (int i = r0; i < 64; i += 4) {
        int n = base + i;
        if (n >= N_NODES) break;
        int g = batch[n];
        if (g != cur) {
            if (cur >= 0) {
                float* p = sums + (long)cur * HID + c4;
                atomicAdd(p + 0, a0); atomicAdd(p + 1, a1);
                atomicAdd(p + 2, a2); atomicAdd(p + 3, a3);
            }
            cur = g;
            a0 = a1 = a2 = a3 = 0.f;
        }
        ushort4 v = *(const ushort4*)(h + (long)n * HID + c4);
        a0 += bf2f(v.x); a1 += bf2f(v.y); a2 += bf2f(v.z); a3 += bf2f(v.w);
    }
    if (cur >= 0) {
        float* p = sums + (long)cur * HID + c4;
        atomicAdd(p + 0, a0); atomicAdd(p + 1, a1);
        atomicAdd(p + 2, a2); atomicAdd(p + 3, a3);
    }
}

__global__ void count_kernel(const int* __restrict__ batch, float* __restrict__ counts) {
    int n = blockIdx.x * blockDim.x + threadIdx.x;
    if (n < N_NODES) atomicAdd(&counts[batch[n]], 1.0f);
}

// ===========================================================================
// Head MLP (fp32): one block per graph.
// ===========================================================================
__global__ __launch_bounds__(256) void final_mlp_kernel(
    const float* __restrict__ sums, const float* __restrict__ counts,
    const float* __restrict__ w1, const float* __restrict__ b1,
    const float* __restrict__ w2, const float* __restrict__ b2,
    float* __restrict__ out) {
    __shared__ float row[HID];
    __shared__ float hid[HID];
    int g = blockIdx.x;
    int t = threadIdx.x;
    float cnt = fmaxf(counts[g], 1.0f);
    row[t] = sums[(long)g * HID + t] / cnt;
    __syncthreads();
    float acc = b1[t];
    for (int k = 0; k < HID; ++k) acc += row[k] * w1[k * HID + t];
    hid[t] = fmaxf(acc, 0.f);
    __syncthreads();
    if (t < OUT_C) {
        float o = b2[t];
        for (int k = 0; k < HID; ++k) o += hid[k] * w2[k * OUT_C + t];
        out[(long)g * OUT_C + t] = o;
    }
}

// ---------------------------------------------------------------------------
extern "C" void kernel_launch(void* const* d_in, const int* in_sizes, int n_in,
                              void* d_out, int out_size, void* d_ws, size_t ws_size,
                              hipStream_t stream) {
    const float* x     = (const float*)d_in[0];
    const int*   ei    = (const int*)d_in[1];
    const int*   batch = (const int*)d_in[2];
    const int*   src   = ei;
    const int*   dst   = ei + N_EDGES;

    const float* c_w1[3] = { (const float*)d_in[3],  (const float*)d_in[7],  (const float*)d_in[11] };
    const float* c_b1[3] = { (const float*)d_in[4],  (const float*)d_in[8],  (const float*)d_in[12] };
    const float* c_w2[3] = { (const float*)d_in[5],  (const float*)d_in[9],  (const float*)d_in[13] };
    const float* c_b2[3] = { (const float*)d_in[6],  (const float*)d_in[10], (const float*)d_in[14] };
    const float* out_w1 = (const float*)d_in[15];
    const float* out_b1 = (const float*)d_in[16];
    const float* out_w2 = (const float*)d_in[17];
    const float* out_b2 = (const float*)d_in[18];

    // ---- Workspace layout (16B aligned regions) ----
    char* p = (char*)d_ws;
    auto alloc = [&](size_t bytes) {
        char* r = p;
        p += (bytes + 15) & ~(size_t)15;
        return r;
    };
    ushort* xbf  = (ushort*)alloc((size_t)N_NODES * IN_C * 2);
    ushort* bufA = (ushort*)alloc((size_t)N_NODES * HID * 2);
    ushort* bufB = (ushort*)alloc((size_t)N_NODES * HID * 2);
    ushort* bufC = (ushort*)alloc((size_t)N_NODES * HID * 2);
    ushort* wt[6];
    wt[0] = (ushort*)alloc((size_t)IN_C * HID * 2);        // c0_w1^T: 256 x 128
    for (int i = 1; i < 6; ++i) wt[i] = (ushort*)alloc((size_t)HID * HID * 2);
    float* sums   = (float*)alloc((size_t)N_GRAPHS * HID * 4);
    float* counts = (float*)alloc((size_t)N_GRAPHS * 4);
    int* deg       = (int*)alloc((size_t)N_NODES * 4);
    int* rowptr    = (int*)alloc((size_t)(N_NODES + 1) * 4);
    int* blockSums = (int*)alloc(256 * 4);
    int* cursor    = (int*)alloc((size_t)N_NODES * 4);
    int* srcSorted = (int*)alloc((size_t)N_EDGES * 4);

    const int nb = (N_NODES + 255) / 256;

    // ---- Prep: casts ----
    {
        int n4 = N_NODES * IN_C / 4;
        cast_x_kernel<<<(n4 + 255) / 256, 256, 0, stream>>>(x, xbf, n4);
    }
    transpose_cast_kernel<<<(IN_C * HID + 255) / 256, 256, 0, stream>>>(c_w1[0], wt[0], IN_C, HID);
    transpose_cast_kernel<<<(HID * HID + 255) / 256, 256, 0, stream>>>(c_w2[0], wt[1], HID, HID);
    transpose_cast_kernel<<<(HID * HID + 255) / 256, 256, 0, stream>>>(c_w1[1], wt[2], HID, HID);
    transpose_cast_kernel<<<(HID * HID + 255) / 256, 256, 0, stream>>>(c_w2[1], wt[3], HID, HID);
    transpose_cast_kernel<<<(HID * HID + 255) / 256, 256, 0, stream>>>(c_w1[2], wt[4], HID, HID);
    transpose_cast_kernel<<<(HID * HID + 255) / 256, 256, 0, stream>>>(c_w2[2], wt[5], HID, HID);

    // ---- Build CSR by dst ----
    hipMemsetAsync(deg, 0, sizeof(int) * N_NODES, stream);
    deg_kernel<<<(N_EDGES + 255) / 256, 256, 0, stream>>>(dst, deg);
    scan_block<<<nb, 256, 0, stream>>>(deg, rowptr, blockSums);
    scan_sums<<<1, 256, 0, stream>>>(blockSums, nb);
    add_offsets<<<nb, 256, 0, stream>>>(rowptr, blockSums, rowptr);
    hipMemcpyAsync(cursor, rowptr, sizeof(int) * N_NODES, hipMemcpyDeviceToDevice, stream);
    bucket_edges<<<(N_EDGES + 255) / 256, 256, 0, stream>>>(src, dst, cursor, srcSorted);

    const int aggGrid = (N_NODES + 3) / 4;       // 12500
    const int gemmGrid = (N_NODES + 63) / 64;    // 782

    // ---- Layer 0 (C_in = 128) ----
    gin_aggregate_bf<IN_C><<<aggGrid, 256, 0, stream>>>(xbf, rowptr, srcSorted, bufB);
    gemm_direct<IN_C><<<gemmGrid, 256, 0, stream>>>(bufB, wt[0], c_b1[0], bufC, N_NODES, 1);
    gemm_direct<HID><<<gemmGrid, 256, 0, stream>>>(bufC, wt[1], c_b2[0], bufA, N_NODES, 1);

    // ---- Layers 1, 2 (C = 256) ----
    for (int li = 1; li < 3; ++li) {
        gin_aggregate_bf<HID><<<aggGrid, 256, 0, stream>>>(bufA, rowptr, srcSorted, bufB);
        gemm_direct<HID><<<gemmGrid, 256, 0, stream>>>(bufB, wt[2 * li], c_b1[li], bufC, N_NODES, 1);
        gemm_direct<HID><<<gemmGrid, 256, 0, stream>>>(bufC, wt[2 * li + 1], c_b2[li], bufA, N_NODES, 1);
    }

    // ---- Global mean pool ----
    hipMemsetAsync(sums, 0, sizeof(float) * (size_t)N_GRAPHS * HID, stream);
    hipMemsetAsync(counts, 0, sizeof(float) * N_GRAPHS, stream);
    pool_kernel_bf<<<(N_NODES + 63) / 64, 256, 0, stream>>>(bufA, batch, sums);
    count_kernel<<<(N_NODES + 255) / 256, 256, 0, stream>>>(batch, counts);

    // ---- Head MLP (fp32) ----
    final_mlp_kernel<<<N_GRAPHS, 256, 0, stream>>>(sums, counts, out_w1, out_b1,
                                                   out_w2, out_b2, (float*)d_out);
}

// Round 6
// 576.033 us; speedup vs baseline: 1.3015x; 1.1164x over previous
//
#include <hip/hip_runtime.h>

#define N_NODES 50000
#define N_EDGES 800000
#define N_GRAPHS 512
#define IN_C 128
#define HID 256
#define OUT_C 16

typedef __attribute__((ext_vector_type(8))) short short8;
typedef __attribute__((ext_vector_type(4))) float f32x4;

__device__ __forceinline__ float bf2f(unsigned short u) {
    return __uint_as_float(((unsigned int)u) << 16);
}
__device__ __forceinline__ unsigned short f2bf(float f) {
    unsigned int u = __float_as_uint(f);
    u += 0x7fff + ((u >> 16) & 1);   // RNE
    return (unsigned short)(u >> 16);
}

// ===========================================================================
// Prep: fp32 -> bf16 casts.
// ===========================================================================
__global__ void cast_x_kernel(const float* __restrict__ in, ushort* __restrict__ out, int n4) {
    int i = blockIdx.x * blockDim.x + threadIdx.x;
    if (i >= n4) return;
    float4 v = *(const float4*)(in + (long)i * 4);
    ushort4 o;
    o.x = f2bf(v.x); o.y = f2bf(v.y); o.z = f2bf(v.z); o.w = f2bf(v.w);
    *(ushort4*)(out + (long)i * 4) = o;
}

// w: K x N fp32 (row-major) -> wt: N x K bf16 (transposed)
__global__ void transpose_cast_kernel(const float* __restrict__ w, ushort* __restrict__ wt,
                                      int K, int N) {
    int i = blockIdx.x * blockDim.x + threadIdx.x;
    if (i >= N * K) return;
    int n = i / K;
    int k = i - n * K;
    wt[i] = f2bf(w[(long)k * N + n]);
}

// ===========================================================================
// CSR build: deg histogram -> 2-level exclusive scan -> bucket edges by dst.
// ===========================================================================
__global__ void deg_kernel(const int* __restrict__ dst, int* __restrict__ deg) {
    int e = blockIdx.x * blockDim.x + threadIdx.x;
    if (e < N_EDGES) atomicAdd(&deg[dst[e]], 1);
}

__global__ __launch_bounds__(256) void scan_block(const int* __restrict__ deg,
                                                  int* __restrict__ partial,
                                                  int* __restrict__ blockSums) {
    __shared__ int s[256];
    int t = threadIdx.x;
    int i = blockIdx.x * 256 + t;
    int v = (i < N_NODES) ? deg[i] : 0;
    s[t] = v;
    __syncthreads();
    #pragma unroll
    for (int off = 1; off < 256; off <<= 1) {
        int add = (t >= off) ? s[t - off] : 0;
        __syncthreads();
        s[t] += add;
        __syncthreads();
    }
    if (i < N_NODES) partial[i] = s[t] - v;
    if (t == 255) blockSums[blockIdx.x] = s[255];
}

__global__ __launch_bounds__(256) void scan_sums(int* __restrict__ blockSums, int nb) {
    __shared__ int s[256];
    int t = threadIdx.x;
    int v = (t < nb) ? blockSums[t] : 0;
    s[t] = v;
    __syncthreads();
    #pragma unroll
    for (int off = 1; off < 256; off <<= 1) {
        int add = (t >= off) ? s[t - off] : 0;
        __syncthreads();
        s[t] += add;
        __syncthreads();
    }
    if (t < nb) blockSums[t] = s[t] - v;
}

__global__ void add_offsets(const int* __restrict__ partial,
                            const int* __restrict__ blockSums,
                            int* __restrict__ rowptr) {
    int i = blockIdx.x * 256 + threadIdx.x;
    if (i < N_NODES) rowptr[i] = partial[i] + blockSums[blockIdx.x];
    if (i == 0) rowptr[N_NODES] = N_EDGES;
}

__global__ void bucket_edges(const int* __restrict__ src, const int* __restrict__ dst,
                             int* __restrict__ cursor, int* __restrict__ srcSorted) {
    int e = blockIdx.x * blockDim.x + threadIdx.x;
    if (e >= N_EDGES) return;
    int p = atomicAdd(&cursor[dst[e]], 1);
    srcSorted[p] = src[e];
}

// ===========================================================================
// Aggregation (bf16, fp32 accumulate): out[n] = h[n] + sum h[src].
// One wave per node; lane owns C/64 channels; neighbor loop unrolled x8
// (avg degree 16 -> usually 2 iterations with 8 gathers in flight).
// ===========================================================================
template <int C>
__global__ __launch_bounds__(256) void gin_aggregate_bf(const ushort* __restrict__ h,
                                                        const int* __restrict__ rowptr,
                                                        const int* __restrict__ srcIdx,
                                                        ushort* __restrict__ out) {
    constexpr int VEC = C / 64;   // 4 (C=256) or 2 (C=128)
    int wave = threadIdx.x >> 6;
    int lane = threadIdx.x & 63;
    int node = blockIdx.x * 4 + wave;
    if (node >= N_NODES) return;
    int coff = lane * VEC;

    float acc[VEC];
    {
        const ushort* hp = h + (long)node * C + coff;
        if constexpr (VEC == 4) {
            ushort4 s = *(const ushort4*)hp;
            acc[0] = bf2f(s.x); acc[1] = bf2f(s.y); acc[2] = bf2f(s.z); acc[3] = bf2f(s.w);
        } else {
            ushort2 s = *(const ushort2*)hp;
            acc[0] = bf2f(s.x); acc[1] = bf2f(s.y);
        }
    }

    int beg = rowptr[node], end = rowptr[node + 1];
    int k = beg;
    for (; k + 8 <= end; k += 8) {
        int si[8];
        #pragma unroll
        for (int u = 0; u < 8; ++u) si[u] = srcIdx[k + u];
        if constexpr (VEC == 4) {
            ushort4 r[8];
            #pragma unroll
            for (int u = 0; u < 8; ++u) r[u] = *(const ushort4*)(h + (long)si[u] * C + coff);
            #pragma unroll
            for (int u = 0; u < 8; ++u) {
                acc[0] += bf2f(r[u].x); acc[1] += bf2f(r[u].y);
                acc[2] += bf2f(r[u].z); acc[3] += bf2f(r[u].w);
            }
        } else {
            ushort2 r[8];
            #pragma unroll
            for (int u = 0; u < 8; ++u) r[u] = *(const ushort2*)(h + (long)si[u] * C + coff);
            #pragma unroll
            for (int u = 0; u < 8; ++u) {
                acc[0] += bf2f(r[u].x); acc[1] += bf2f(r[u].y);
            }
        }
    }
    for (; k + 4 <= end; k += 4) {
        int si[4];
        #pragma unroll
        for (int u = 0; u < 4; ++u) si[u] = srcIdx[k + u];
        if constexpr (VEC == 4) {
            ushort4 r[4];
            #pragma unroll
            for (int u = 0; u < 4; ++u) r[u] = *(const ushort4*)(h + (long)si[u] * C + coff);
            #pragma unroll
            for (int u = 0; u < 4; ++u) {
                acc[0] += bf2f(r[u].x); acc[1] += bf2f(r[u].y);
                acc[2] += bf2f(r[u].z); acc[3] += bf2f(r[u].w);
            }
        } else {
            ushort2 r[4];
            #pragma unroll
            for (int u = 0; u < 4; ++u) r[u] = *(const ushort2*)(h + (long)si[u] * C + coff);
            #pragma unroll
            for (int u = 0; u < 4; ++u) {
                acc[0] += bf2f(r[u].x); acc[1] += bf2f(r[u].y);
            }
        }
    }
    for (; k < end; ++k) {
        int s = srcIdx[k];
        if constexpr (VEC == 4) {
            ushort4 r = *(const ushort4*)(h + (long)s * C + coff);
            acc[0] += bf2f(r.x); acc[1] += bf2f(r.y); acc[2] += bf2f(r.z); acc[3] += bf2f(r.w);
        } else {
            ushort2 r = *(const ushort2*)(h + (long)s * C + coff);
            acc[0] += bf2f(r.x); acc[1] += bf2f(r.y);
        }
    }

    ushort* op = out + (long)node * C + coff;
    if constexpr (VEC == 4) {
        ushort4 o;
        o.x = f2bf(acc[0]); o.y = f2bf(acc[1]); o.z = f2bf(acc[2]); o.w = f2bf(acc[3]);
        *(ushort4*)op = o;
    } else {
        ushort2 o;
        o.x = f2bf(acc[0]); o.y = f2bf(acc[1]);
        *(ushort2*)op = o;
    }
}

// ===========================================================================
// Fused 2-layer MLP: out = relu(relu(A@W1+b1)@W2+b2), bf16 in/out.
// Block = 64 rows, 4 waves; wave wv owns cols [wv*64, wv*64+64).
// Phase B: a-frags + W1t-frags straight from global (gemm_direct pattern),
//          h1 -> LDS Hs (chunk layout, pitch 65 slots of 16B).
// Phase C: a-frags from LDS (b128, ~2-way max conflicts), W2t from L2-hot
//          global, guarded store to out.
// LDS = 33.3 KB -> ~3 blocks/CU at ~130 VGPR (12 waves), same as gemm_direct.
// ===========================================================================
template <int K1>
__global__ __launch_bounds__(256) void gin_mlp(
    const ushort* __restrict__ A,    // M x K1 bf16 (agg output)
    const ushort* __restrict__ w1t,  // 256 x K1 bf16
    const float* __restrict__ b1,
    const ushort* __restrict__ w2t,  // 256 x 256 bf16
    const float* __restrict__ b2,
    ushort* __restrict__ out,        // M x 256 bf16
    int M)
{
    __shared__ short Hs[32 * 65 * 8];   // 33,280 B

    int t = threadIdx.x;
    int lane = t & 63;
    int wv = t >> 6;
    int quad = lane >> 4;
    int l15 = lane & 15;
    int row0 = blockIdx.x * 64;
    int col0 = wv * 64;

    const f32x4 zero = {0.f, 0.f, 0.f, 0.f};
    f32x4 acc[4][4];

    // ---------------- Phase B: h1 = relu(A @ W1 + b1) -> Hs ----------------
    #pragma unroll
    for (int i = 0; i < 4; ++i)
        #pragma unroll
        for (int j = 0; j < 4; ++j) acc[i][j] = zero;

    long arow[4];
    #pragma unroll
    for (int i = 0; i < 4; ++i) {
        int r = row0 + i * 16 + l15;
        if (r >= M) r = M - 1;          // clamp; stores guarded
        arow[i] = (long)r * K1;
    }
    long brow[4];
    #pragma unroll
    for (int j = 0; j < 4; ++j)
        brow[j] = (long)(col0 + j * 16 + l15) * K1;

    #pragma unroll
    for (int s = 0; s < K1 / 32; ++s) {
        int ko = s * 32 + quad * 8;
        short8 a[4], b[4];
        #pragma unroll
        for (int i = 0; i < 4; ++i) a[i] = *(const short8*)(A + arow[i] + ko);
        #pragma unroll
        for (int j = 0; j < 4; ++j) b[j] = *(const short8*)(w1t + brow[j] + ko);
        #pragma unroll
        for (int i = 0; i < 4; ++i)
            #pragma unroll
            for (int j = 0; j < 4; ++j)
                acc[i][j] = __builtin_amdgcn_mfma_f32_16x16x32_bf16(a[i], b[j], acc[i][j], 0, 0, 0);
    }

    {
        float bv[4];
        #pragma unroll
        for (int j = 0; j < 4; ++j) bv[j] = b1[col0 + j * 16 + l15];
        #pragma unroll
        for (int i = 0; i < 4; ++i)
            #pragma unroll
            for (int j = 0; j < 4; ++j) {
                int col = col0 + j * 16 + l15;
                int q2 = col >> 3, sub = col & 7;
                #pragma unroll
                for (int r = 0; r < 4; ++r) {
                    int row = i * 16 + quad * 4 + r;
                    float o = fmaxf(acc[i][j][r] + bv[j], 0.f);
                    Hs[(q2 * 65 + row) * 8 + sub] = (short)f2bf(o);
                }
            }
    }
    __syncthreads();

    // ---------------- Phase C: out = relu(h1 @ W2 + b2) ----------------
    #pragma unroll
    for (int i = 0; i < 4; ++i)
        #pragma unroll
        for (int j = 0; j < 4; ++j) acc[i][j] = zero;

    long brow2[4];
    #pragma unroll
    for (int j = 0; j < 4; ++j)
        brow2[j] = (long)(col0 + j * 16 + l15) * 256;

    #pragma unroll
    for (int s = 0; s < 8; ++s) {
        short8 a[4], b[4];
        #pragma unroll
        for (int i = 0; i < 4; ++i)
            a[i] = *(const short8*)&Hs[((s * 4 + quad) * 65 + i * 16 + l15) * 8];
        #pragma unroll
        for (int j = 0; j < 4; ++j)
            b[j] = *(const short8*)(w2t + brow2[j] + s * 32 + quad * 8);
        #pragma unroll
        for (int i = 0; i < 4; ++i)
            #pragma unroll
            for (int j = 0; j < 4; ++j)
                acc[i][j] = __builtin_amdgcn_mfma_f32_16x16x32_bf16(a[i], b[j], acc[i][j], 0, 0, 0);
    }

    {
        float bv[4];
        #pragma unroll
        for (int j = 0; j < 4; ++j) bv[j] = b2[col0 + j * 16 + l15];
        #pragma unroll
        for (int i = 0; i < 4; ++i)
            #pragma unroll
            for (int r = 0; r < 4; ++r) {
                int row = row0 + i * 16 + quad * 4 + r;
                if (row >= M) continue;
                #pragma unroll
                for (int j = 0; j < 4; ++j) {
                    float o = fmaxf(acc[i][j][r] + bv[j], 0.f);
                    out[(long)row * 256 + col0 + j * 16 + l15] = f2bf(o);
                }
            }
    }
}

// ===========================================================================
// Mean-pool (bf16 h -> fp32 sums): run-length flush, batch is sorted.
// ===========================================================================
__global__ __launch_bounds__(256) void pool_kernel_bf(const ushort* __restrict__ h,
                                                      const int* __restrict__ batch,
                                                      float* __restrict__ sums) {
    int base = blockIdx.x * 64;
    int t = threadIdx.x;
    int c4 = (t & 63) << 2;
    int r0 = t >> 6;
    float a0 = 0.f, a1 = 0.f, a2 = 0.f, a3 = 0.f;
    int cur = -1;
    for (int i = r0; i < 64; i += 4) {
        int n = base + i;
        if (n >= N_NODES) break;
        int g = batch[n];
        if (g != cur) {
            if (cur >= 0) {
                float* p = sums + (long)cur * HID + c4;
                atomicAdd(p + 0, a0); atomicAdd(p + 1, a1);
                atomicAdd(p + 2, a2); atomicAdd(p + 3, a3);
            }
            cur = g;
            a0 = a1 = a2 = a3 = 0.f;
        }
        ushort4 v = *(const ushort4*)(h + (long)n * HID + c4);
        a0 += bf2f(v.x); a1 += bf2f(v.y); a2 += bf2f(v.z); a3 += bf2f(v.w);
    }
    if (cur >= 0) {
        float* p = sums + (long)cur * HID + c4;
        atomicAdd(p + 0, a0); atomicAdd(p + 1, a1);
        atomicAdd(p + 2, a2); atomicAdd(p + 3, a3);
    }
}

__global__ void count_kernel(const int* __restrict__ batch, float* __restrict__ counts) {
    int n = blockIdx.x * blockDim.x + threadIdx.x;
    if (n < N_NODES) atomicAdd(&counts[batch[n]], 1.0f);
}

// ===========================================================================
// Head MLP (fp32): one block per graph.
// ===========================================================================
__global__ __launch_bounds__(256) void final_mlp_kernel(
    const float* __restrict__ sums, const float* __restrict__ counts,
    const float* __restrict__ w1, const float* __restrict__ b1,
    const float* __restrict__ w2, const float* __restrict__ b2,
    float* __restrict__ out) {
    __shared__ float row[HID];
    __shared__ float hid[HID];
    int g = blockIdx.x;
    int t = threadIdx.x;
    float cnt = fmaxf(counts[g], 1.0f);
    row[t] = sums[(long)g * HID + t] / cnt;
    __syncthreads();
    float acc = b1[t];
    for (int k = 0; k < HID; ++k) acc += row[k] * w1[k * HID + t];
    hid[t] = fmaxf(acc, 0.f);
    __syncthreads();
    if (t < OUT_C) {
        float o = b2[t];
        for (int k = 0; k < HID; ++k) o += hid[k] * w2[k * OUT_C + t];
        out[(long)g * OUT_C + t] = o;
    }
}

// ---------------------------------------------------------------------------
extern "C" void kernel_launch(void* const* d_in, const int* in_sizes, int n_in,
                              void* d_out, int out_size, void* d_ws, size_t ws_size,
                              hipStream_t stream) {
    const float* x     = (const float*)d_in[0];
    const int*   ei    = (const int*)d_in[1];
    const int*   batch = (const int*)d_in[2];
    const int*   src   = ei;
    const int*   dst   = ei + N_EDGES;

    const float* c_w1[3] = { (const float*)d_in[3],  (const float*)d_in[7],  (const float*)d_in[11] };
    const float* c_b1[3] = { (const float*)d_in[4],  (const float*)d_in[8],  (const float*)d_in[12] };
    const float* c_w2[3] = { (const float*)d_in[5],  (const float*)d_in[9],  (const float*)d_in[13] };
    const float* c_b2[3] = { (const float*)d_in[6],  (const float*)d_in[10], (const float*)d_in[14] };
    const float* out_w1 = (const float*)d_in[15];
    const float* out_b1 = (const float*)d_in[16];
    const float* out_w2 = (const float*)d_in[17];
    const float* out_b2 = (const float*)d_in[18];

    // ---- Workspace layout (16B aligned regions) ----
    char* p = (char*)d_ws;
    auto alloc = [&](size_t bytes) {
        char* r = p;
        p += (bytes + 15) & ~(size_t)15;
        return r;
    };
    ushort* xbf  = (ushort*)alloc((size_t)N_NODES * IN_C * 2);
    ushort* bufA = (ushort*)alloc((size_t)N_NODES * HID * 2);
    ushort* bufB = (ushort*)alloc((size_t)N_NODES * HID * 2);
    ushort* wt[6];
    wt[0] = (ushort*)alloc((size_t)IN_C * HID * 2);        // c0_w1^T: 256 x 128
    for (int i = 1; i < 6; ++i) wt[i] = (ushort*)alloc((size_t)HID * HID * 2);
    float* sums   = (float*)alloc((size_t)N_GRAPHS * HID * 4);
    float* counts = (float*)alloc((size_t)N_GRAPHS * 4);
    int* deg       = (int*)alloc((size_t)N_NODES * 4);
    int* rowptr    = (int*)alloc((size_t)(N_NODES + 1) * 4);
    int* blockSums = (int*)alloc(256 * 4);
    int* cursor    = (int*)alloc((size_t)N_NODES * 4);
    int* srcSorted = (int*)alloc((size_t)N_EDGES * 4);

    const int nb = (N_NODES + 255) / 256;

    // ---- Prep: casts ----
    {
        int n4 = N_NODES * IN_C / 4;
        cast_x_kernel<<<(n4 + 255) / 256, 256, 0, stream>>>(x, xbf, n4);
    }
    transpose_cast_kernel<<<(IN_C * HID + 255) / 256, 256, 0, stream>>>(c_w1[0], wt[0], IN_C, HID);
    transpose_cast_kernel<<<(HID * HID + 255) / 256, 256, 0, stream>>>(c_w2[0], wt[1], HID, HID);
    transpose_cast_kernel<<<(HID * HID + 255) / 256, 256, 0, stream>>>(c_w1[1], wt[2], HID, HID);
    transpose_cast_kernel<<<(HID * HID + 255) / 256, 256, 0, stream>>>(c_w2[1], wt[3], HID, HID);
    transpose_cast_kernel<<<(HID * HID + 255) / 256, 256, 0, stream>>>(c_w1[2], wt[4], HID, HID);
    transpose_cast_kernel<<<(HID * HID + 255) / 256, 256, 0, stream>>>(c_w2[2], wt[5], HID, HID);

    // ---- Build CSR by dst ----
    hipMemsetAsync(deg, 0, sizeof(int) * N_NODES, stream);
    deg_kernel<<<(N_EDGES + 255) / 256, 256, 0, stream>>>(dst, deg);
    scan_block<<<nb, 256, 0, stream>>>(deg, rowptr, blockSums);
    scan_sums<<<1, 256, 0, stream>>>(blockSums, nb);
    add_offsets<<<nb, 256, 0, stream>>>(rowptr, blockSums, rowptr);
    hipMemcpyAsync(cursor, rowptr, sizeof(int) * N_NODES, hipMemcpyDeviceToDevice, stream);
    bucket_edges<<<(N_EDGES + 255) / 256, 256, 0, stream>>>(src, dst, cursor, srcSorted);

    const int aggGrid = (N_NODES + 3) / 4;       // 12500
    const int mlpGrid = (N_NODES + 63) / 64;     // 782

    // ---- Layer 0 (C_in = 128) ----
    gin_aggregate_bf<IN_C><<<aggGrid, 256, 0, stream>>>(xbf, rowptr, srcSorted, bufB);
    gin_mlp<IN_C><<<mlpGrid, 256, 0, stream>>>(bufB, wt[0], c_b1[0], wt[1], c_b2[0], bufA, N_NODES);

    // ---- Layers 1, 2 (C = 256) ----
    for (int li = 1; li < 3; ++li) {
        gin_aggregate_bf<HID><<<aggGrid, 256, 0, stream>>>(bufA, rowptr, srcSorted, bufB);
        gin_mlp<HID><<<mlpGrid, 256, 0, stream>>>(bufB, wt[2 * li], c_b1[li], wt[2 * li + 1], c_b2[li], bufA, N_NODES);
    }

    // ---- Global mean pool ----
    hipMemsetAsync(sums, 0, sizeof(float) * (size_t)N_GRAPHS * HID, stream);
    hipMemsetAsync(counts, 0, sizeof(float) * N_GRAPHS, stream);
    pool_kernel_bf<<<(N_NODES + 63) / 64, 256, 0, stream>>>(bufA, batch, sums);
    count_kernel<<<(N_NODES + 255) / 256, 256, 0, stream>>>(batch, counts);

    // ---- Head MLP (fp32) ----
    final_mlp_kernel<<<N_GRAPHS, 256, 0, stream>>>(sums, counts, out_w1, out_b1,
                                                   out_w2, out_b2, (float*)d_out);
}

// Round 7
// 518.837 us; speedup vs baseline: 1.4449x; 1.1102x over previous
//
#include <hip/hip_runtime.h>

#define N_NODES 50000
#define N_EDGES 800000
#define N_GRAPHS 512
#define IN_C 128
#define HID 256
#define OUT_C 16

typedef __attribute__((ext_vector_type(8))) short short8;
typedef __attribute__((ext_vector_type(4))) float f32x4;

__device__ __forceinline__ float bf2f(unsigned short u) {
    return __uint_as_float(((unsigned int)u) << 16);
}
__device__ __forceinline__ unsigned short f2bf(float f) {
    unsigned int u = __float_as_uint(f);
    u += 0x7fff + ((u >> 16) & 1);   // RNE
    return (unsigned short)(u >> 16);
}

// ===========================================================================
// Prep (single dispatch): x -> bf16, six weight transposes (K x 256 fp32 ->
// 256 x K bf16), zero deg, zero sums+counts (contiguous).
// ===========================================================================
struct PrepArgs {
    const float* x;
    const float* w[6];      // K x 256 row-major; K = 128 for w[0], else 256
    ushort* xbf;
    ushort* wt[6];
    int* deg;
    float* sums;            // counts immediately follows sums in ws
};

__global__ __launch_bounds__(256) void prep_kernel(PrepArgs a) {
    const int X4    = N_NODES * IN_C / 4;          // 1,600,000 ushort4 items
    const int TW    = IN_C * HID;                  // 32768
    const int TH    = HID * HID;                   // 65536
    const int TBASE = X4;
    const int TEND  = TBASE + TW + 5 * TH;
    const int D4    = N_NODES / 4;                 // 12500 int4
    const int DBASE = TEND;
    const int SBASE = DBASE + D4;
    const int S4    = (N_GRAPHS * HID + N_GRAPHS) / 4;  // sums+counts float4
    const long total = (long)SBASE + S4;

    long stride = (long)gridDim.x * blockDim.x;
    for (long i = (long)blockIdx.x * blockDim.x + threadIdx.x; i < total; i += stride) {
        if (i < X4) {
            float4 v = ((const float4*)a.x)[i];
            ushort4 o;
            o.x = f2bf(v.x); o.y = f2bf(v.y); o.z = f2bf(v.z); o.w = f2bf(v.w);
            ((ushort4*)a.xbf)[i] = o;
        } else if (i < TEND) {
            long r = i - TBASE;
            int wi, shift;
            long off;
            if (r < TW) { wi = 0; shift = 7; off = r; }
            else { r -= TW; wi = 1 + (int)(r / TH); shift = 8; off = r % TH; }
            int n = (int)(off >> shift);
            int k = (int)(off - ((long)n << shift));
            a.wt[wi][off] = f2bf(a.w[wi][(long)k * HID + n]);
        } else if (i < SBASE) {
            ((int4*)a.deg)[i - DBASE] = make_int4(0, 0, 0, 0);
        } else {
            ((float4*)a.sums)[i - SBASE] = make_float4(0.f, 0.f, 0.f, 0.f);
        }
    }
}

// ===========================================================================
// CSR build: deg histogram -> 2-level exclusive scan -> bucket edges by dst.
// ===========================================================================
__global__ void deg_kernel(const int* __restrict__ dst, int* __restrict__ deg) {
    int e = blockIdx.x * blockDim.x + threadIdx.x;
    if (e < N_EDGES) atomicAdd(&deg[dst[e]], 1);
}

__global__ __launch_bounds__(256) void scan_block(const int* __restrict__ deg,
                                                  int* __restrict__ partial,
                                                  int* __restrict__ blockSums) {
    __shared__ int s[256];
    int t = threadIdx.x;
    int i = blockIdx.x * 256 + t;
    int v = (i < N_NODES) ? deg[i] : 0;
    s[t] = v;
    __syncthreads();
    #pragma unroll
    for (int off = 1; off < 256; off <<= 1) {
        int add = (t >= off) ? s[t - off] : 0;
        __syncthreads();
        s[t] += add;
        __syncthreads();
    }
    if (i < N_NODES) partial[i] = s[t] - v;
    if (t == 255) blockSums[blockIdx.x] = s[255];
}

__global__ __launch_bounds__(256) void scan_sums(int* __restrict__ blockSums, int nb) {
    __shared__ int s[256];
    int t = threadIdx.x;
    int v = (t < nb) ? blockSums[t] : 0;
    s[t] = v;
    __syncthreads();
    #pragma unroll
    for (int off = 1; off < 256; off <<= 1) {
        int add = (t >= off) ? s[t - off] : 0;
        __syncthreads();
        s[t] += add;
        __syncthreads();
    }
    if (t < nb) blockSums[t] = s[t] - v;
}

// writes rowptr AND cursor (kills the d2d memcpy dispatch)
__global__ void add_offsets(const int* __restrict__ partial,
                            const int* __restrict__ blockSums,
                            int* __restrict__ rowptr,
                            int* __restrict__ cursor) {
    int i = blockIdx.x * 256 + threadIdx.x;
    if (i < N_NODES) {
        int v = partial[i] + blockSums[blockIdx.x];
        rowptr[i] = v;
        cursor[i] = v;
    }
    if (i == 0) rowptr[N_NODES] = N_EDGES;
}

__global__ void bucket_edges(const int* __restrict__ src, const int* __restrict__ dst,
                             int* __restrict__ cursor, int* __restrict__ srcSorted) {
    int e = blockIdx.x * blockDim.x + threadIdx.x;
    if (e >= N_EDGES) return;
    int p = atomicAdd(&cursor[dst[e]], 1);
    srcSorted[p] = src[e];
}

// ===========================================================================
// Aggregation: out[n] = h[n] + sum h[src]. One wave per node; each lane loads
// ushort8 (16B) so C/8 lanes cover a row and the wave processes NPW = 64/(C/8)
// neighbors per load-inst (2 for C=256, 4 for C=128) with zero degree
// divergence. Epilogue: shfl_xor cross-sub reduction, sub 0 stores 16B.
// ===========================================================================
template <int C>
__global__ __launch_bounds__(256) void gin_aggregate_bf(const ushort* __restrict__ h,
                                                        const int* __restrict__ rowptr,
                                                        const int* __restrict__ srcIdx,
                                                        ushort* __restrict__ out) {
    constexpr int LPN = C / 8;      // lanes per node row: 32 (C=256), 16 (C=128)
    constexpr int NPW = 64 / LPN;   // neighbors in flight: 2 or 4
    int wave = threadIdx.x >> 6;
    int lane = threadIdx.x & 63;
    int node = blockIdx.x * 4 + wave;
    if (node >= N_NODES) return;
    int sub = lane / LPN;
    int l = lane & (LPN - 1);
    int coff = l * 8;

    float acc[8];
    #pragma unroll
    for (int v = 0; v < 8; ++v) acc[v] = 0.f;

    if (sub == 0) {
        short8 s = *(const short8*)(h + (long)node * C + coff);
        #pragma unroll
        for (int v = 0; v < 8; ++v) acc[v] += bf2f((unsigned short)s[v]);
    }

    int beg = rowptr[node], end = rowptr[node + 1];
    int k = beg;
    for (; k + 4 * NPW <= end; k += 4 * NPW) {
        int si[4];
        #pragma unroll
        for (int u = 0; u < 4; ++u) si[u] = srcIdx[k + u * NPW + sub];
        short8 r[4];
        #pragma unroll
        for (int u = 0; u < 4; ++u) r[u] = *(const short8*)(h + (long)si[u] * C + coff);
        #pragma unroll
        for (int u = 0; u < 4; ++u)
            #pragma unroll
            for (int v = 0; v < 8; ++v) acc[v] += bf2f((unsigned short)r[u][v]);
    }
    for (; k < end; k += NPW) {
        int idx = k + sub;
        if (idx < end) {
            int s = srcIdx[idx];
            short8 r = *(const short8*)(h + (long)s * C + coff);
            #pragma unroll
            for (int v = 0; v < 8; ++v) acc[v] += bf2f((unsigned short)r[v]);
        }
    }

    // cross-sub reduction
    #pragma unroll
    for (int v = 0; v < 8; ++v) {
        if constexpr (NPW == 4) acc[v] += __shfl_xor(acc[v], 16);
        acc[v] += __shfl_xor(acc[v], 32);
    }

    if (sub == 0) {
        short8 o;
        #pragma unroll
        for (int v = 0; v < 8; ++v) o[v] = (short)f2bf(acc[v]);
        *(short8*)(out + (long)node * C + coff) = o;
    }
}

// ===========================================================================
// Fused 2-layer MLP: out = relu(relu(A@W1+b1)@W2+b2), bf16 in/out.
// (unchanged from R6 — proven)
// ===========================================================================
template <int K1>
__global__ __launch_bounds__(256) void gin_mlp(
    const ushort* __restrict__ A,    // M x K1 bf16 (agg output)
    const ushort* __restrict__ w1t,  // 256 x K1 bf16
    const float* __restrict__ b1,
    const ushort* __restrict__ w2t,  // 256 x 256 bf16
    const float* __restrict__ b2,
    ushort* __restrict__ out,        // M x 256 bf16
    int M)
{
    __shared__ short Hs[32 * 65 * 8];   // 33,280 B

    int t = threadIdx.x;
    int lane = t & 63;
    int wv = t >> 6;
    int quad = lane >> 4;
    int l15 = lane & 15;
    int row0 = blockIdx.x * 64;
    int col0 = wv * 64;

    const f32x4 zero = {0.f, 0.f, 0.f, 0.f};
    f32x4 acc[4][4];

    // ---------------- Phase B: h1 = relu(A @ W1 + b1) -> Hs ----------------
    #pragma unroll
    for (int i = 0; i < 4; ++i)
        #pragma unroll
        for (int j = 0; j < 4; ++j) acc[i][j] = zero;

    long arow[4];
    #pragma unroll
    for (int i = 0; i < 4; ++i) {
        int r = row0 + i * 16 + l15;
        if (r >= M) r = M - 1;          // clamp; stores guarded
        arow[i] = (long)r * K1;
    }
    long brow[4];
    #pragma unroll
    for (int j = 0; j < 4; ++j)
        brow[j] = (long)(col0 + j * 16 + l15) * K1;

    #pragma unroll
    for (int s = 0; s < K1 / 32; ++s) {
        int ko = s * 32 + quad * 8;
        short8 a[4], b[4];
        #pragma unroll
        for (int i = 0; i < 4; ++i) a[i] = *(const short8*)(A + arow[i] + ko);
        #pragma unroll
        for (int j = 0; j < 4; ++j) b[j] = *(const short8*)(w1t + brow[j] + ko);
        #pragma unroll
        for (int i = 0; i < 4; ++i)
            #pragma unroll
            for (int j = 0; j < 4; ++j)
                acc[i][j] = __builtin_amdgcn_mfma_f32_16x16x32_bf16(a[i], b[j], acc[i][j], 0, 0, 0);
    }

    {
        float bv[4];
        #pragma unroll
        for (int j = 0; j < 4; ++j) bv[j] = b1[col0 + j * 16 + l15];
        #pragma unroll
        for (int i = 0; i < 4; ++i)
            #pragma unroll
            for (int j = 0; j < 4; ++j) {
                int col = col0 + j * 16 + l15;
                int q2 = col >> 3, sub = col & 7;
                #pragma unroll
                for (int r = 0; r < 4; ++r) {
                    int row = i * 16 + quad * 4 + r;
                    float o = fmaxf(acc[i][j][r] + bv[j], 0.f);
                    Hs[(q2 * 65 + row) * 8 + sub] = (short)f2bf(o);
                }
            }
    }
    __syncthreads();

    // ---------------- Phase C: out = relu(h1 @ W2 + b2) ----------------
    #pragma unroll
    for (int i = 0; i < 4; ++i)
        #pragma unroll
        for (int j = 0; j < 4; ++j) acc[i][j] = zero;

    long brow2[4];
    #pragma unroll
    for (int j = 0; j < 4; ++j)
        brow2[j] = (long)(col0 + j * 16 + l15) * 256;

    #pragma unroll
    for (int s = 0; s < 8; ++s) {
        short8 a[4], b[4];
        #pragma unroll
        for (int i = 0; i < 4; ++i)
            a[i] = *(const short8*)&Hs[((s * 4 + quad) * 65 + i * 16 + l15) * 8];
        #pragma unroll
        for (int j = 0; j < 4; ++j)
            b[j] = *(const short8*)(w2t + brow2[j] + s * 32 + quad * 8);
        #pragma unroll
        for (int i = 0; i < 4; ++i)
            #pragma unroll
            for (int j = 0; j < 4; ++j)
                acc[i][j] = __builtin_amdgcn_mfma_f32_16x16x32_bf16(a[i], b[j], acc[i][j], 0, 0, 0);
    }

    {
        float bv[4];
        #pragma unroll
        for (int j = 0; j < 4; ++j) bv[j] = b2[col0 + j * 16 + l15];
        #pragma unroll
        for (int i = 0; i < 4; ++i)
            #pragma unroll
            for (int r = 0; r < 4; ++r) {
                int row = row0 + i * 16 + quad * 4 + r;
                if (row >= M) continue;
                #pragma unroll
                for (int j = 0; j < 4; ++j) {
                    float o = fmaxf(acc[i][j][r] + bv[j], 0.f);
                    out[(long)row * 256 + col0 + j * 16 + l15] = f2bf(o);
                }
            }
    }
}

// ===========================================================================
// Mean-pool (bf16 h -> fp32 sums) with fused node-count. Run-length flush.
// ===========================================================================
__global__ __launch_bounds__(256) void pool_kernel_bf(const ushort* __restrict__ h,
                                                      const int* __restrict__ batch,
                                                      float* __restrict__ sums,
                                                      float* __restrict__ counts) {
    int base = blockIdx.x * 64;
    int t = threadIdx.x;
    int c4 = (t & 63) << 2;
    int r0 = t >> 6;
    bool cntOwner = (t & 63) == 0;   // 4 threads, disjoint node subsets
    float a0 = 0.f, a1 = 0.f, a2 = 0.f, a3 = 0.f, cnt = 0.f;
    int cur = -1;
    for (int i = r0; i < 64; i += 4) {
        int n = base + i;
        if (n >= N_NODES) break;
        int g = batch[n];
        if (g != cur) {
            if (cur >= 0) {
                float* p = sums + (long)cur * HID + c4;
                atomicAdd(p + 0, a0); atomicAdd(p + 1, a1);
                atomicAdd(p + 2, a2); atomicAdd(p + 3, a3);
                if (cntOwner) atomicAdd(&counts[cur], cnt);
            }
            cur = g;
            a0 = a1 = a2 = a3 = 0.f;
            cnt = 0.f;
        }
        ushort4 v = *(const ushort4*)(h + (long)n * HID + c4);
        a0 += bf2f(v.x); a1 += bf2f(v.y); a2 += bf2f(v.z); a3 += bf2f(v.w);
        cnt += 1.f;
    }
    if (cur >= 0) {
        float* p = sums + (long)cur * HID + c4;
        atomicAdd(p + 0, a0); atomicAdd(p + 1, a1);
        atomicAdd(p + 2, a2); atomicAdd(p + 3, a3);
        if (cntOwner) atomicAdd(&counts[cur], cnt);
    }
}

// ===========================================================================
// Head MLP (fp32): one block per graph.
// ===========================================================================
__global__ __launch_bounds__(256) void final_mlp_kernel(
    const float* __restrict__ sums, const float* __restrict__ counts,
    const float* __restrict__ w1, const float* __restrict__ b1,
    const float* __restrict__ w2, const float* __restrict__ b2,
    float* __restrict__ out) {
    __shared__ float row[HID];
    __shared__ float hid[HID];
    int g = blockIdx.x;
    int t = threadIdx.x;
    float cnt = fmaxf(counts[g], 1.0f);
    row[t] = sums[(long)g * HID + t] / cnt;
    __syncthreads();
    float acc = b1[t];
    for (int k = 0; k < HID; ++k) acc += row[k] * w1[k * HID + t];
    hid[t] = fmaxf(acc, 0.f);
    __syncthreads();
    if (t < OUT_C) {
        float o = b2[t];
        for (int k = 0; k < HID; ++k) o += hid[k] * w2[k * OUT_C + t];
        out[(long)g * OUT_C + t] = o;
    }
}

// ---------------------------------------------------------------------------
extern "C" void kernel_launch(void* const* d_in, const int* in_sizes, int n_in,
                              void* d_out, int out_size, void* d_ws, size_t ws_size,
                              hipStream_t stream) {
    const float* x     = (const float*)d_in[0];
    const int*   ei    = (const int*)d_in[1];
    const int*   batch = (const int*)d_in[2];
    const int*   src   = ei;
    const int*   dst   = ei + N_EDGES;

    const float* c_w1[3] = { (const float*)d_in[3],  (const float*)d_in[7],  (const float*)d_in[11] };
    const float* c_b1[3] = { (const float*)d_in[4],  (const float*)d_in[8],  (const float*)d_in[12] };
    const float* c_w2[3] = { (const float*)d_in[5],  (const float*)d_in[9],  (const float*)d_in[13] };
    const float* c_b2[3] = { (const float*)d_in[6],  (const float*)d_in[10], (const float*)d_in[14] };
    const float* out_w1 = (const float*)d_in[15];
    const float* out_b1 = (const float*)d_in[16];
    const float* out_w2 = (const float*)d_in[17];
    const float* out_b2 = (const float*)d_in[18];

    // ---- Workspace layout (16B aligned regions; sums+counts CONTIGUOUS) ----
    char* p = (char*)d_ws;
    auto alloc = [&](size_t bytes) {
        char* r = p;
        p += (bytes + 15) & ~(size_t)15;
        return r;
    };
    ushort* xbf  = (ushort*)alloc((size_t)N_NODES * IN_C * 2);
    ushort* bufA = (ushort*)alloc((size_t)N_NODES * HID * 2);
    ushort* bufB = (ushort*)alloc((size_t)N_NODES * HID * 2);
    ushort* wt[6];
    wt[0] = (ushort*)alloc((size_t)IN_C * HID * 2);        // c0_w1^T: 256 x 128
    for (int i = 1; i < 6; ++i) wt[i] = (ushort*)alloc((size_t)HID * HID * 2);
    float* sums   = (float*)alloc((size_t)N_GRAPHS * HID * 4);   // counts follows
    float* counts = (float*)alloc((size_t)N_GRAPHS * 4);
    int* deg       = (int*)alloc((size_t)N_NODES * 4);
    int* rowptr    = (int*)alloc((size_t)(N_NODES + 1) * 4);
    int* blockSums = (int*)alloc(256 * 4);
    int* cursor    = (int*)alloc((size_t)N_NODES * 4);
    int* srcSorted = (int*)alloc((size_t)N_EDGES * 4);

    const int nb = (N_NODES + 255) / 256;

    // ---- Prep: one dispatch for casts + transposes + zeroing ----
    {
        PrepArgs a;
        a.x = x;
        a.w[0] = c_w1[0]; a.w[1] = c_w2[0];
        a.w[2] = c_w1[1]; a.w[3] = c_w2[1];
        a.w[4] = c_w1[2]; a.w[5] = c_w2[2];
        a.xbf = xbf;
        for (int i = 0; i < 6; ++i) a.wt[i] = wt[i];
        a.deg = deg;
        a.sums = sums;
        prep_kernel<<<2048, 256, 0, stream>>>(a);
    }

    // ---- Build CSR by dst ----
    deg_kernel<<<(N_EDGES + 255) / 256, 256, 0, stream>>>(dst, deg);
    scan_block<<<nb, 256, 0, stream>>>(deg, rowptr, blockSums);
    scan_sums<<<1, 256, 0, stream>>>(blockSums, nb);
    add_offsets<<<nb, 256, 0, stream>>>(rowptr, blockSums, rowptr, cursor);
    bucket_edges<<<(N_EDGES + 255) / 256, 256, 0, stream>>>(src, dst, cursor, srcSorted);

    const int aggGrid = (N_NODES + 3) / 4;       // 12500
    const int mlpGrid = (N_NODES + 63) / 64;     // 782

    // ---- Layer 0 (C_in = 128) ----
    gin_aggregate_bf<IN_C><<<aggGrid, 256, 0, stream>>>(xbf, rowptr, srcSorted, bufB);
    gin_mlp<IN_C><<<mlpGrid, 256, 0, stream>>>(bufB, wt[0], c_b1[0], wt[1], c_b2[0], bufA, N_NODES);

    // ---- Layers 1, 2 (C = 256) ----
    for (int li = 1; li < 3; ++li) {
        gin_aggregate_bf<HID><<<aggGrid, 256, 0, stream>>>(bufA, rowptr, srcSorted, bufB);
        gin_mlp<HID><<<mlpGrid, 256, 0, stream>>>(bufB, wt[2 * li], c_b1[li], wt[2 * li + 1], c_b2[li], bufA, N_NODES);
    }

    // ---- Global mean pool (count fused) ----
    pool_kernel_bf<<<(N_NODES + 63) / 64, 256, 0, stream>>>(bufA, batch, sums, counts);

    // ---- Head MLP (fp32) ----
    final_mlp_kernel<<<N_GRAPHS, 256, 0, stream>>>(sums, counts, out_w1, out_b1,
                                                   out_w2, out_b2, (float*)d_out);
}